// Round 4
// baseline (258.450 us; speedup 1.0000x reference)
//
#include <hip/hip_runtime.h>

// N=64, C=128, S=H*W=1024. f32 I/O; bf16 MFMA (16x16x32) internally.
// ws: 4KB stats (2-way split partials) + kT 16MB bf16 [n][s][c] + vN 16MB
// bf16 [n][c][s]. attn: 512-thr blocks (16 waves/CU), no-max softmax,
// Ps aliases Ks (4 barriers/itile), chunk-XOR swizzled LDS everywhere.

#define NS 64
#define CD 128
#define SD 1024
#define MEL (CD*SD)
#define SCALE 0.08838834764831845f  // 1/sqrt(128)

typedef __attribute__((ext_vector_type(4))) float floatx4;
typedef __attribute__((ext_vector_type(8))) short short8;
typedef __attribute__((ext_vector_type(4))) short short4v;

typedef __attribute__((address_space(1))) const void global_cvoid;
typedef __attribute__((address_space(3))) void lds_void;

__device__ __forceinline__ void gl16(const void* g, void* l) {
  __builtin_amdgcn_global_load_lds((global_cvoid*)g, (lds_void*)l, 16, 0, 0);
}
__device__ __forceinline__ unsigned short f2bf(float f) {
  union { float f; unsigned int i; } v; v.f = f;
  unsigned int i = v.i;
  return (unsigned short)((i + 0x7fffu + ((i >> 16) & 1u)) >> 16);  // RNE
}
__device__ __forceinline__ short8 ld8_bf16(const float* __restrict__ p) {
  floatx4 a = *(const floatx4*)p;
  floatx4 b = *(const floatx4*)(p + 4);
  short8 r;
  r[0] = (short)f2bf(a[0]); r[1] = (short)f2bf(a[1]);
  r[2] = (short)f2bf(a[2]); r[3] = (short)f2bf(a[3]);
  r[4] = (short)f2bf(b[0]); r[5] = (short)f2bf(b[1]);
  r[6] = (short)f2bf(b[2]); r[7] = (short)f2bf(b[3]);
  return r;
}
__device__ __forceinline__ floatx4 mfma16(short8 a, short8 b, floatx4 c) {
  return __builtin_amdgcn_mfma_f32_16x16x32_bf16(a, b, c, 0, 0, 0);
}

// ---------------- Kernel 1: per-(tensor,sample) sum/sumsq, 2-way split ------
__global__ __launch_bounds__(512) void stats_kernel(
    const float* __restrict__ q, const float* __restrict__ k,
    const float* __restrict__ v, float* __restrict__ sums)
{
  int tn = blockIdx.x;            // 0..191
  int part = blockIdx.y;          // 0..1
  int t = tn >> 6;
  const float* x = (t == 0 ? q : (t == 1 ? k : v)) + (size_t)(tn & 63) * MEL
                   + part * (MEL / 2);
  float s1 = 0.f, s2 = 0.f;
  for (int it = 0; it < 32; ++it) {
    floatx4 u = *(const floatx4*)(x + it * 2048 + threadIdx.x * 4);
#pragma unroll
    for (int j = 0; j < 4; ++j) { float f = u[j]; s1 += f; s2 += f * f; }
  }
#pragma unroll
  for (int off = 32; off; off >>= 1) {
    s1 += __shfl_xor(s1, off, 64);
    s2 += __shfl_xor(s2, off, 64);
  }
  __shared__ float r1[8], r2[8];
  int w = threadIdx.x >> 6;
  if ((threadIdx.x & 63) == 0) { r1[w] = s1; r2[w] = s2; }
  __syncthreads();
  if (threadIdx.x == 0) {
    float a = 0.f, b = 0.f;
#pragma unroll
    for (int i = 0; i < 8; ++i) { a += r1[i]; b += r2[i]; }
    sums[part * 192 + tn] = a; sums[384 + part * 192 + tn] = b;
  }
}

// ---------------- Kernel 2: fused LN + 1x1-conv for K and V ----------------
// Both outputs through LDS transpose -> b128 coalesced global stores.
// t==0: kT[n][s][c] (D = W.X, [c_out][s]); t==1: vN[n][c][s] (D = X.W^T, [s][c_out]).
__global__ __launch_bounds__(512, 4) void proj_kernel(
  const float* __restrict__ k, const float* __restrict__ v,
  const float* __restrict__ l2w, const float* __restrict__ l2b,
  const float* __restrict__ l3w, const float* __restrict__ l3b,
  const float* __restrict__ wk, const float* __restrict__ bk,
  const float* __restrict__ wv, const float* __restrict__ bv,
  const float* __restrict__ sums,
  unsigned short* __restrict__ kT, unsigned short* __restrict__ vN)
{
  int n  = blockIdx.x, t = blockIdx.y, st = blockIdx.z;
  const float* x  = (t == 0 ? k : v) + (size_t)n * MEL;
  const float* lw = (t == 0 ? l2w : l3w);
  const float* lb = (t == 0 ? l2b : l3b);
  const float* W  = (t == 0 ? wk : wv);
  const float* Bs = (t == 0 ? bk : bv);

  int si = (t + 1) * 64 + n;
  float s1 = sums[si] + sums[192 + si];
  float s2 = sums[384 + si] + sums[576 + si];
  float mu  = s1 * (1.f / MEL);
  float var = s2 * (1.f / MEL) - mu * mu;
  float rs  = rsqrtf(var + 1e-5f);
  float a_ln = rs, b_ln = -mu * rs;

  // Xt[128][128] shorts, chunk-XOR swizzle: chunk' = chunk ^ (row & 7)
  __shared__ __align__(16) unsigned short Xt[128 * 128];

  int tid = threadIdx.x;
  int cb = tid & 15, sb = (tid >> 4) & 15, half = tid >> 8;
  int s0 = st * 128;

  // stage LN(x) transposed [s][c]
  unsigned int w32[8][2];
#pragma unroll
  for (int pr = 0; pr < 2; ++pr) {
    int c0 = cb * 8 + half * 4 + pr * 2;
    const float* xp0 = x  + (size_t)c0 * SD + s0 + sb * 8;
    const float* wp0 = lw + (size_t)c0 * SD + s0 + sb * 8;
    const float* bp0 = lb + (size_t)c0 * SD + s0 + sb * 8;
    float xv0[8], xv1[8], wv0[8], wv1[8], bv0[8], bv1[8];
    *(floatx4*)xv0 = *(const floatx4*)xp0;       *(floatx4*)(xv0+4) = *(const floatx4*)(xp0+4);
    *(floatx4*)xv1 = *(const floatx4*)(xp0+SD);  *(floatx4*)(xv1+4) = *(const floatx4*)(xp0+SD+4);
    *(floatx4*)wv0 = *(const floatx4*)wp0;       *(floatx4*)(wv0+4) = *(const floatx4*)(wp0+4);
    *(floatx4*)wv1 = *(const floatx4*)(wp0+SD);  *(floatx4*)(wv1+4) = *(const floatx4*)(wp0+SD+4);
    *(floatx4*)bv0 = *(const floatx4*)bp0;       *(floatx4*)(bv0+4) = *(const floatx4*)(bp0+4);
    *(floatx4*)bv1 = *(const floatx4*)(bp0+SD);  *(floatx4*)(bv1+4) = *(const floatx4*)(bp0+SD+4);
#pragma unroll
    for (int js = 0; js < 8; ++js) {
      unsigned int lo = f2bf((xv0[js] * a_ln + b_ln) * wv0[js] + bv0[js]);
      unsigned int hi = f2bf((xv1[js] * a_ln + b_ln) * wv1[js] + bv1[js]);
      w32[js][pr] = lo | (hi << 16);
    }
  }
#pragma unroll
  for (int js = 0; js < 8; ++js) {
    // row = sb*8+js, row&7 = js; chunk cb -> cb^js
    unsigned int* d = (unsigned int*)&Xt[(sb * 8 + js) * 128 + ((cb ^ js) * 8) + half * 4];
    d[0] = w32[js][0]; d[1] = w32[js][1];
  }
  __syncthreads();

  int lane = tid & 63, w = tid >> 6;       // 8 waves
  int quad = lane >> 4, l16 = lane & 15;

  short8 Wf[4];
#pragma unroll
  for (int kk = 0; kk < 4; ++kk)
    Wf[kk] = ld8_bf16(W + (w * 16 + l16) * CD + kk * 32 + quad * 8);

  floatx4 acc[8];
  floatx4 zz = {0.f, 0.f, 0.f, 0.f};
#pragma unroll
  for (int sblk = 0; sblk < 8; ++sblk) acc[sblk] = zz;
#pragma unroll
  for (int kk = 0; kk < 4; ++kk)
#pragma unroll
    for (int sblk = 0; sblk < 8; ++sblk) {
      short8 Xf = *(const short8*)&Xt[(sblk * 16 + l16) * 128 +
                                      (((kk * 4 + quad) ^ (l16 & 7)) * 8)];
      acc[sblk] = (t == 0) ? mfma16(Wf[kk], Xf, acc[sblk])   // D[c_out][s]
                           : mfma16(Xf, Wf[kk], acc[sblk]);  // D[s][c_out]
    }
  __syncthreads();   // Xt reads done; reuse as output tile

  if (t == 0) {
    float bsv[4];
#pragma unroll
    for (int r = 0; r < 4; ++r) bsv[r] = Bs[w * 16 + quad * 4 + r];
#pragma unroll
    for (int sblk = 0; sblk < 8; ++sblk) {
      short4v pk;
#pragma unroll
      for (int r = 0; r < 4; ++r) pk[r] = (short)f2bf(acc[sblk][r] + bsv[r]);
      int row = sblk * 16 + l16;                       // s
      int cblk = w * 2 + (quad >> 1);                  // c chunk
      *(short4v*)&Xt[row * 128 + ((cblk ^ (l16 & 7)) * 8) + (quad & 1) * 4] = pk;
    }
  } else {
    float bsv = Bs[w * 16 + l16];
#pragma unroll
    for (int sblk = 0; sblk < 8; ++sblk) {
      short4v pk;
#pragma unroll
      for (int r = 0; r < 4; ++r) pk[r] = (short)f2bf(acc[sblk][r] + bsv);
      int row = w * 16 + l16;                          // c
      int cblk = sblk * 2 + (quad >> 1);               // s chunk
      *(short4v*)&Xt[row * 128 + ((cblk ^ (l16 & 7)) * 8) + (quad & 1) * 4] = pk;
    }
  }
  __syncthreads();

  unsigned short* outp = (t == 0 ? kT : vN);
#pragma unroll
  for (int it = 0; it < 4; ++it) {
    int id = it * 512 + tid;
    int row = id >> 4, ch = id & 15;
    short8 u = *(const short8*)&Xt[row * 128 + ((ch ^ (row & 7)) * 8)];
    size_t g;
    if (t == 0) g = (size_t)n * MEL + (size_t)(s0 + row) * CD + ch * 8;
    else        g = (size_t)n * MEL + (size_t)row * SD + s0 + ch * 8;
    *(short8*)(outp + g) = u;
  }
}

// ------- Kernel 3: fused q-proj + flash attention, 512 threads/block -------
__global__ __launch_bounds__(512, 4) void attn_kernel(
  const float* __restrict__ qraw, const float* __restrict__ l1w,
  const float* __restrict__ l1b, const float* __restrict__ wq,
  const float* __restrict__ bq,
  const unsigned short* __restrict__ kT, const unsigned short* __restrict__ vN,
  const float* __restrict__ sums, float* __restrict__ out)
{
  int n = blockIdx.x, jt = blockIdx.y;
  int j0 = jt * 128;

  // [0,32768) Xt[128][128] (phase A) / {Ks[64][128] & Ps[128][64] alias @0,
  //                                     Vs[128][64] @16384}
  // [32768,33792) l_part[2][128] f32
  __shared__ __align__(16) char smem[33792];
  unsigned short* Xt = (unsigned short*)smem;
  unsigned short* Ks = (unsigned short*)smem;            // 16KB
  unsigned short* Ps = (unsigned short*)smem;            // 16KB (alias Ks)
  unsigned short* Vs = (unsigned short*)(smem + 16384);  // 16KB
  float* l_part = (float*)(smem + 32768);                // [2][128]

  int tid = threadIdx.x, lane = tid & 63, w = tid >> 6;  // 8 waves
  int quad = lane >> 4, l16 = lane & 15;

  float s1 = sums[n] + sums[192 + n];
  float s2 = sums[384 + n] + sums[576 + n];
  float mu  = s1 * (1.f / MEL);
  float var = s2 * (1.f / MEL) - mu * mu;
  float rsd = rsqrtf(var + 1e-5f);
  float a_ln = rsd, b_ln = -mu * rsd;
  const float* qb = qraw + (size_t)n * MEL;

  // --- Phase A: LN1(q) -> Xt[j][c] (swizzled) ---
  {
    int cb = tid & 15, sb = (tid >> 4) & 15, half = tid >> 8;
    unsigned int w32[8][2];
#pragma unroll
    for (int pr = 0; pr < 2; ++pr) {
      int c0 = cb * 8 + half * 4 + pr * 2;
      const float* xp0 = qb  + (size_t)c0 * SD + j0 + sb * 8;
      const float* wp0 = l1w + (size_t)c0 * SD + j0 + sb * 8;
      const float* bp0 = l1b + (size_t)c0 * SD + j0 + sb * 8;
      float xv0[8], xv1[8], wv0[8], wv1[8], bv0[8], bv1[8];
      *(floatx4*)xv0 = *(const floatx4*)xp0;       *(floatx4*)(xv0+4) = *(const floatx4*)(xp0+4);
      *(floatx4*)xv1 = *(const floatx4*)(xp0+SD);  *(floatx4*)(xv1+4) = *(const floatx4*)(xp0+SD+4);
      *(floatx4*)wv0 = *(const floatx4*)wp0;       *(floatx4*)(wv0+4) = *(const floatx4*)(wp0+4);
      *(floatx4*)wv1 = *(const floatx4*)(wp0+SD);  *(floatx4*)(wv1+4) = *(const floatx4*)(wp0+SD+4);
      *(floatx4*)bv0 = *(const floatx4*)bp0;       *(floatx4*)(bv0+4) = *(const floatx4*)(bp0+4);
      *(floatx4*)bv1 = *(const floatx4*)(bp0+SD);  *(floatx4*)(bv1+4) = *(const floatx4*)(bp0+SD+4);
#pragma unroll
      for (int js = 0; js < 8; ++js) {
        unsigned int lo = f2bf((xv0[js] * a_ln + b_ln) * wv0[js] + bv0[js]);
        unsigned int hi = f2bf((xv1[js] * a_ln + b_ln) * wv1[js] + bv1[js]);
        w32[js][pr] = lo | (hi << 16);
      }
    }
#pragma unroll
    for (int js = 0; js < 8; ++js) {
      unsigned int* d = (unsigned int*)&Xt[(sb * 8 + js) * 128 + ((cb ^ js) * 8) + half * 4];
      d[0] = w32[js][0]; d[1] = w32[js][1];
    }
  }
  __syncthreads();

  floatx4 zz = {0.f, 0.f, 0.f, 0.f};
  // q-projection: wave w -> c_out tile w; D[c_out][j]
  {
    short8 Wf[4];
#pragma unroll
    for (int kk = 0; kk < 4; ++kk)
      Wf[kk] = ld8_bf16(wq + (w * 16 + l16) * CD + kk * 32 + quad * 8);
    floatx4 accq[8];
#pragma unroll
    for (int nb = 0; nb < 8; ++nb) accq[nb] = zz;
#pragma unroll
    for (int kk = 0; kk < 4; ++kk)
#pragma unroll
      for (int nb = 0; nb < 8; ++nb) {
        short8 Bf = *(const short8*)&Xt[(nb * 16 + l16) * 128 +
                                        (((kk * 4 + quad) ^ (l16 & 7)) * 8)];
        accq[nb] = mfma16(Wf[kk], Bf, accq[nb]);
      }
    __syncthreads();   // Xt reads done; write projected q back as [j][c]
    float bqs[4];
#pragma unroll
    for (int r = 0; r < 4; ++r) bqs[r] = bq[w * 16 + quad * 4 + r];
#pragma unroll
    for (int nb = 0; nb < 8; ++nb) {
      short4v pk;
#pragma unroll
      for (int r = 0; r < 4; ++r) pk[r] = (short)f2bf(accq[nb][r] + bqs[r]);
      int row = nb * 16 + l16;                 // j
      int cblk = w * 2 + (quad >> 1);          // c chunk
      *(short4v*)&Xt[row * 128 + ((cblk ^ (l16 & 7)) * 8) + (quad & 1) * 4] = pk;
    }
  }
  __syncthreads();

  // Pin Q B-frags: wave w -> nt-pair (w>>1): j rows ((w>>1)*2+ntl)*16+l16
  short8 Qf[2][4];
#pragma unroll
  for (int ntl = 0; ntl < 2; ++ntl) {
    int row = ((w >> 1) * 2 + ntl) * 16 + l16;
#pragma unroll
    for (int kk = 0; kk < 4; ++kk)
      Qf[ntl][kk] = *(const short8*)&Xt[row * 128 + (((kk * 4 + quad) ^ (l16 & 7)) * 8)];
  }
  __syncthreads();   // Xt about to be overwritten by Ks/Vs

  floatx4 Oc[2][4];
#pragma unroll
  for (int mi = 0; mi < 2; ++mi)
#pragma unroll
    for (int nb = 0; nb < 4; ++nb) Oc[mi][nb] = zz;
  float lsum[2] = {0.f, 0.f};

  const unsigned short* kbase0 = kT + (size_t)n * MEL;
  const unsigned short* vbase0 = vN + (size_t)n * MEL;

  for (int itile = 0; itile < 16; ++itile) {
    int i0 = itile * 64;
    const unsigned short* kbase = kbase0 + (size_t)i0 * CD;
#pragma unroll
    for (int it = 0; it < 2; ++it) {   // Ks[i][c], chunk-swizzled by i&7
      int nch = it * 512 + tid;
      int i = nch >> 4, cc = nch & 15;
      int csrc = (cc & 8) | ((cc & 7) ^ (i & 7));
      gl16(kbase + i * CD + csrc * 8, Ks + nch * 8);
    }
#pragma unroll
    for (int it = 0; it < 2; ++it) {   // Vs[c][i], chunk-swizzled by c&7
      int nch = it * 512 + tid;
      int c = nch >> 3, ci = nch & 7;
      int isrc = ci ^ (c & 7);
      gl16(vbase0 + (size_t)c * SD + i0 + isrc * 8, Vs + nch * 8);
    }
    __syncthreads();

    // QK: S[i][j]; wave w: mt in {(w&1)*2,+1}, nt in {(w>>1)*2,+1}
    floatx4 Sa[2][2];
#pragma unroll
    for (int a = 0; a < 2; ++a) { Sa[a][0] = zz; Sa[a][1] = zz; }
#pragma unroll
    for (int kk = 0; kk < 4; ++kk) {
      short8 Kf[2];
#pragma unroll
      for (int mtl = 0; mtl < 2; ++mtl) {
        int row = ((w & 1) * 2 + mtl) * 16 + l16;
        Kf[mtl] = *(const short8*)&Ks[row * 128 + (((kk * 4 + quad) ^ (l16 & 7)) * 8)];
      }
#pragma unroll
      for (int mtl = 0; mtl < 2; ++mtl)
#pragma unroll
        for (int ntl = 0; ntl < 2; ++ntl)
          Sa[mtl][ntl] = mfma16(Kf[mtl], Qf[ntl][kk], Sa[mtl][ntl]);
    }
    __syncthreads();   // all Ks reads done before Ps overwrites (alias)

    // no-max softmax; Ps[j][i] b64 writes
#pragma unroll
    for (int mtl = 0; mtl < 2; ++mtl) {
      int mt = (w & 1) * 2 + mtl;
#pragma unroll
      for (int ntl = 0; ntl < 2; ++ntl) {
        float p0 = __expf(Sa[mtl][ntl][0] * SCALE);
        float p1 = __expf(Sa[mtl][ntl][1] * SCALE);
        float p2 = __expf(Sa[mtl][ntl][2] * SCALE);
        float p3 = __expf(Sa[mtl][ntl][3] * SCALE);
        lsum[ntl] += (p0 + p1) + (p2 + p3);
        short4v pk;
        pk[0] = (short)f2bf(p0); pk[1] = (short)f2bf(p1);
        pk[2] = (short)f2bf(p2); pk[3] = (short)f2bf(p3);
        int jrow = ((w >> 1) * 2 + ntl) * 16 + l16;
        int cis = (mt * 2 + (quad >> 1)) ^ (l16 & 7);
        *(short4v*)&Ps[jrow * 64 + cis * 8 + (quad & 1) * 4] = pk;
      }
    }
    __syncthreads();

    // PV: O[c][j] += V.P; wave w: mi in {(w&3)*2,+1}, nb in {(w>>2)*4..+3}
#pragma unroll
    for (int kk = 0; kk < 2; ++kk) {
      short8 Vf[2];
#pragma unroll
      for (int mi = 0; mi < 2; ++mi) {
        int c = ((w & 3) * 2 + mi) * 16 + l16;
        Vf[mi] = *(const short8*)&Vs[c * 64 + (((kk * 4 + quad) ^ (l16 & 7)) * 8)];
      }
#pragma unroll
      for (int nb = 0; nb < 4; ++nb) {
        int j = ((w >> 2) * 4 + nb) * 16 + l16;
        short8 Pf = *(const short8*)&Ps[j * 64 + (((kk * 4 + quad) ^ (l16 & 7)) * 8)];
        Oc[0][nb] = mfma16(Vf[0], Pf, Oc[0][nb]);
        Oc[1][nb] = mfma16(Vf[1], Pf, Oc[1][nb]);
      }
    }
    __syncthreads();   // PV reads done; next itile may overwrite Ks/Ps/Vs
  }

  // cross-quad then cross-wave reduction of softmax denominators
#pragma unroll
  for (int ntl = 0; ntl < 2; ++ntl) {
    lsum[ntl] += __shfl_xor(lsum[ntl], 16, 64);
    lsum[ntl] += __shfl_xor(lsum[ntl], 32, 64);
  }
  if (lane < 16) {
#pragma unroll
    for (int ntl = 0; ntl < 2; ++ntl)
      l_part[(w & 1) * 128 + ((w >> 1) * 2 + ntl) * 16 + lane] = lsum[ntl];
  }
  __syncthreads();

  // epilogue: out[c][j] = O/l + LN1(query)[c][j]
  float linv[4];
#pragma unroll
  for (int nb = 0; nb < 4; ++nb) {
    int j = ((w >> 2) * 4 + nb) * 16 + l16;
    linv[nb] = 1.f / (l_part[j] + l_part[128 + j]);
  }
#pragma unroll
  for (int mi = 0; mi < 2; ++mi) {
#pragma unroll
    for (int r = 0; r < 4; ++r) {
      int c = ((w & 3) * 2 + mi) * 16 + quad * 4 + r;
      const float* qp = qb  + (size_t)c * SD + j0;
      const float* wp = l1w + (size_t)c * SD + j0;
      const float* bp = l1b + (size_t)c * SD + j0;
      float* op = out + (size_t)n * MEL + (size_t)c * SD + j0;
#pragma unroll
      for (int nb = 0; nb < 4; ++nb) {
        int j = ((w >> 2) * 4 + nb) * 16 + l16;
        float qn = (qp[j] * a_ln + b_ln) * wp[j] + bp[j];
        op[j] = Oc[mi][nb][r] * linv[nb] + qn;
      }
    }
  }
}

// ---------------- host launch ----------------
extern "C" void kernel_launch(void* const* d_in, const int* in_sizes, int n_in,
                              void* d_out, int out_size, void* d_ws, size_t ws_size,
                              hipStream_t stream)
{
  const float* q   = (const float*)d_in[0];
  const float* k   = (const float*)d_in[1];
  const float* v   = (const float*)d_in[2];
  const float* l1w = (const float*)d_in[3];
  const float* l1b = (const float*)d_in[4];
  const float* l2w = (const float*)d_in[5];
  const float* l2b = (const float*)d_in[6];
  const float* l3w = (const float*)d_in[7];
  const float* l3b = (const float*)d_in[8];
  const float* wq  = (const float*)d_in[9];
  const float* bq  = (const float*)d_in[10];
  const float* wk  = (const float*)d_in[11];
  const float* bk  = (const float*)d_in[12];
  const float* wv  = (const float*)d_in[13];
  const float* bv  = (const float*)d_in[14];

  char* ws = (char*)d_ws;
  float* sums = (float*)ws;                          // [768] split partials
  unsigned short* kT = (unsigned short*)(ws + 4096); // [64][1024][128] bf16
  unsigned short* vN = kT + (size_t)NS * MEL;        // [64][128][1024] bf16

  stats_kernel<<<dim3(192, 2), 512, 0, stream>>>(q, k, v, sums);
  proj_kernel<<<dim3(64, 2, 8), 512, 0, stream>>>(k, v, l2w, l2b, l3w, l3b,
      wk, bk, wv, bv, sums, kT, vN);
  attn_kernel<<<dim3(64, 8), 512, 0, stream>>>(q, l1w, l1b, wq, bq, kT, vN,
      sums, (float*)d_out);
}